// Round 4
// baseline (77702.002 us; speedup 1.0000x reference)
//
#include <hip/hip_runtime.h>
#include <math.h>

// ---------------------------------------------------------------------------
// LSTMModel round 4: persistent cooperative kernel with HAND-ROLLED barriers
// (epoch counters + agent-scope spin, no grid.sync), deterministic table-based
// stats/logit reduction (no atomics), and gemm work scheduled into barrier
// wait slack. Decomposition as round 3: 256 blocks x 512 thr, each block owns
// 4 h-indices (16 gate cols), both layers' weight slices LDS-resident.
// ---------------------------------------------------------------------------

#define N_   128
#define T_   256
#define QN_  16
#define INX  24
#define H_   1024
#define G4   4096
#define FDIM 768
#define EPS_ 1e-5f
#define K0_  1792
#define K1_  2048
#define W1OFF (16 * K0_)

typedef unsigned short u16;
typedef __attribute__((ext_vector_type(8))) short bf16x8;
typedef __attribute__((ext_vector_type(4))) float f32x4;

__device__ __forceinline__ float sigmoidf_(float v) { return 1.0f / (1.0f + expf(-v)); }

__device__ __forceinline__ u16 f2bf(float f) {
  unsigned u = __float_as_uint(f);
  u += 0x7fffu + ((u >> 16) & 1u);
  return (u16)(u >> 16);
}

// ---- BatchNorm stats over the (N*T, 16) numeric block --------------------
__global__ __launch_bounds__(256) void bn_stats_k(const float* __restrict__ x,
    const float* __restrict__ gamma, const float* __restrict__ beta,
    float* __restrict__ scale, float* __restrict__ shift) {
  int q = blockIdx.x;
  int tid = threadIdx.x;
  float s = 0.f, s2 = 0.f;
  for (int r = tid; r < N_ * T_; r += 256) {
    float v = x[(size_t)r * INX + q];
    s += v; s2 += v * v;
  }
  for (int off = 32; off; off >>= 1) { s += __shfl_down(s, off); s2 += __shfl_down(s2, off); }
  __shared__ float red[2][4];
  int w = tid >> 6;
  if ((tid & 63) == 0) { red[0][w] = s; red[1][w] = s2; }
  __syncthreads();
  if (tid == 0) {
    float S = 0.f, S2 = 0.f;
    for (int i = 0; i < 4; ++i) { S += red[0][i]; S2 += red[1][i]; }
    float m   = S  / (float)(N_ * T_);
    float var = S2 / (float)(N_ * T_) - m * m;
    float rs  = rsqrtf(var + EPS_);
    scale[q] = rs * gamma[q];
    shift[q] = beta[q] - m * rs * gamma[q];
  }
}

// ---- Feature build for ALL steps: ft[t][n][768] bf16 ---------------------
__global__ __launch_bounds__(256) void feats_all_k(const float* __restrict__ x,
    const float* __restrict__ scale, const float* __restrict__ shift,
    const float* __restrict__ QnV, const float* __restrict__ QlV,
    u16* __restrict__ ft) {
  int rid = blockIdx.x;              // t*128 + n
  int t = rid >> 7, n = rid & 127;
  const float* xr = x + ((size_t)n * T_ + t) * INX;
  u16* frow = ft + (size_t)rid * FDIM;
  for (int f = threadIdx.x; f < FDIM; f += 256) {
    int d = f & 31;
    float v;
    if (f < 512) {
      int q = f >> 5;
      v = (xr[q] * scale[q] + shift[q]) * QnV[q * 32 + d];
    } else {
      int cg_ = (f - 512) >> 5;
      int idx = (int)xr[QN_ + cg_] + cg_ * 100;
      v = QlV[idx * 32 + d];
    }
    frow[f] = f2bf(v);
  }
}

// ---- Weight convert: W[k][col] fp32 -> WtP[(bcu*16+v)][k] bf16 -----------
__global__ __launch_bounds__(256) void wconv_k(const float* __restrict__ W,
                                               u16* __restrict__ WtP, int K) {
  __shared__ u16 L[64][72];
  int tid = threadIdx.x;
  int k0 = blockIdx.x * 64, n0 = blockIdx.y * 64;
#pragma unroll
  for (int it = 0; it < 16; ++it) {
    int e = it * 256 + tid;
    int r = e >> 6, c = e & 63;
    L[r][c] = f2bf(W[(size_t)(k0 + r) * G4 + n0 + c]);
  }
  __syncthreads();
  int n = tid >> 2, ks = (tid & 3) << 4;
  int col = n0 + n;
  int bcu = (col & 1023) >> 2;
  int v   = (col >> 10) * 4 + (col & 3);
  u16* dst = WtP + ((size_t)(bcu * 16 + v)) * K + k0 + ks;
#pragma unroll
  for (int j = 0; j < 16; ++j) dst[j] = L[ks + j][n];
}

// ---- barrier primitives ---------------------------------------------------
__device__ __forceinline__ void arrive_(unsigned* c) {
  __hip_atomic_fetch_add(c, 1u, __ATOMIC_RELAXED, __HIP_MEMORY_SCOPE_AGENT);
}
__device__ __forceinline__ void spin_(unsigned* c, unsigned tgt) {
  while (__hip_atomic_load(c, __ATOMIC_RELAXED, __HIP_MEMORY_SCOPE_AGENT) < tgt)
    __builtin_amdgcn_s_sleep(1);
}

// ---- K-partial MFMA: acc += A[rowA, base..base+NK*32) @ W[base..) --------
template<int NK>
__device__ __forceinline__ void gemm_part(f32x4& acc, const u16* __restrict__ aBase,
                                          const u16* wRow, int cb, int swz, int g) {
#pragma unroll 8
  for (int kc = 0; kc < NK; ++kc) {
    bf16x8 a = *(const bf16x8*)(aBase + kc * 32);
    bf16x8 b = *(const bf16x8*)(wRow + (((cb + kc * 4 + g) ^ swz) << 3));
    acc = __builtin_amdgcn_mfma_f32_16x16x32_bf16(a, b, acc, 0, 0, 0);
  }
}

// ---- The persistent recurrence kernel ------------------------------------
__global__ __launch_bounds__(512, 2) void persist_k(
    const u16* __restrict__ WtP0, const u16* __restrict__ WtP1,
    const u16* __restrict__ ft,
    u16* __restrict__ h0, u16* __restrict__ h1,
    const float* __restrict__ b0, const float* __restrict__ b1,
    const float* __restrict__ lng, const float* __restrict__ lnb,
    const float* __restrict__ fcW, const float* __restrict__ fcb,
    float* __restrict__ stats0, float* __restrict__ stats1,
    float* __restrict__ ptab0, float* __restrict__ ptab1,
    float* __restrict__ ltab, unsigned* __restrict__ cnts,
    float* __restrict__ out) {
  __shared__ u16 wlds[16 * K0_ + 16 * K1_];   // 120 KiB
  const int bcu = blockIdx.x, tid = threadIdx.x;
  const int wave = tid >> 6, lane = tid & 63;
  const int vcol = lane & 15, g = lane >> 4;
  const int gg = vcol >> 2, hh = vcol & 3;
  const int swz = vcol & 7;
  const int rowA  = wave * 16 + vcol;
  const int rbase = wave * 16 + g * 4;
  const int hidx  = bcu * 4 + hh;
  const int col0  = gg * 1024 + hidx;

  unsigned* c1a = cnts;
  unsigned* c1b = cnts + 256;
  unsigned* c2  = cnts + 512;
  unsigned* c3a = cnts + 768;
  unsigned* c3b = cnts + 1024;
  unsigned* c4  = cnts + 1280;

  // ---- one-time: weight slices global -> LDS (XOR chunk swizzle) ----
  for (int i = 0; i < 15; ++i) {
    int cid = tid + i * 512;
    if (cid < 3584) {
      int v = cid / 224, ck = cid - v * 224;
      *(bf16x8*)&wlds[v * K0_ + ((ck ^ (v & 7)) << 3)] =
          *(const bf16x8*)&WtP0[((size_t)(bcu * 16 + v)) * K0_ + (ck << 3)];
    } else {
      int c2i = cid - 3584;
      int v = c2i >> 8, ck = c2i & 255;
      *(bf16x8*)&wlds[W1OFF + v * K1_ + ((ck ^ (v & 7)) << 3)] =
          *(const bf16x8*)&WtP1[((size_t)(bcu * 16 + v)) * K1_ + (ck << 3)];
    }
  }
  __syncthreads();

  const float bias0v = b0[col0], bias1v = b1[col0];
  const float lng0v = lng[col0],      lnb0v = lnb[col0];
  const float lng1v = lng[G4 + col0], lnb1v = lnb[G4 + col0];
  const float fw0 = fcW[hidx * 2], fw1 = fcW[hidx * 2 + 1];

  float c0r[4] = {0.f, 0.f, 0.f, 0.f};
  float c1r[4] = {0.f, 0.f, 0.f, 0.f};

  const u16* paH0 = h0 + (size_t)rowA * H_ + g * 8;
  const u16* paH1 = h1 + (size_t)rowA * H_ + g * 8;
  const u16* wb0 = &wlds[vcol * K0_];
  const u16* wb1 = &wlds[W1OFF + vcol * K1_];

  // prologue: accG0 = G0F(0)  (h0 == 0 so G0H(0) contributes nothing)
  f32x4 accG0 = {0.f, 0.f, 0.f, 0.f};
  gemm_part<24>(accG0, ft + (size_t)rowA * FDIM + g * 8, wb0, 128, swz, g);

  f32x4 accb0, accb1;

  for (int t = 0; t < T_; ++t) {
    // ============ phase A: stats0 publish; slack = G1H ===================
#pragma unroll
    for (int r = 0; r < 4; ++r) accb0[r] = accG0[r] + bias0v;
#pragma unroll
    for (int r = 0; r < 4; ++r) {
      float s = accb0[r], q = s * s;
      s += __shfl_xor(s, 1); q += __shfl_xor(q, 1);
      s += __shfl_xor(s, 2); q += __shfl_xor(q, 2);
      if (hh == 0)
        *(float2*)&ptab0[(size_t)bcu * 1024 + ((rbase + r) * 4 + gg) * 2] = make_float2(s, q);
    }
    __syncthreads();
    if (tid == 0) { __threadfence(); arrive_(&c1a[t]); }
    f32x4 accG1 = {0.f, 0.f, 0.f, 0.f};
    gemm_part<32>(accG1, paH1, wb1, 0, swz, g);          // G1H: h1(t-1)
    if (tid == 0) spin_(&c1a[t], 256);
    __syncthreads();
    __threadfence();
    // reduce window: blocks 0..127 reduce stats0; 128..255 do softmax(t-1)
    if (bcu < 128) {
      if (tid < 8) {
        int idx = (bcu * 4 + (tid >> 1)) * 2 + (tid & 1);
        float s = 0.f;
#pragma unroll 8
        for (int b = 0; b < 256; ++b) s += ptab0[(size_t)b * 1024 + idx];
        stats0[idx] = s;
      }
    } else if (t > 0 && tid == 0) {
      int row = bcu - 128;
      float L0 = fcb[0], L1 = fcb[1];
#pragma unroll 8
      for (int b = 0; b < 256; ++b) {
        float2 v = *(const float2*)&ltab[(size_t)b * 256 + row * 2];
        L0 += v.x; L1 += v.y;
      }
      float mx = fmaxf(L0, L1);
      float e0 = expf(L0 - mx), e1 = expf(L1 - mx);
      float inv = 1.f / (e0 + e1);
      out[((size_t)row * T_ + (t - 1)) * 2]     = e0 * inv;
      out[((size_t)row * T_ + (t - 1)) * 2 + 1] = e1 * inv;
    }
    __syncthreads();
    if (tid == 0) {
      __threadfence();
      if (bcu < 128) arrive_(&c1b[t]);
      spin_(&c1b[t], 128);
    }
    __syncthreads();
    __threadfence();

    // ============ phase B: cell0 -> h0(t); slack = G0F(t+1) ==============
#pragma unroll
    for (int r = 0; r < 4; ++r) {
      int srow = rbase + r;
      float sum = stats0[(srow * 4 + gg) * 2];
      float sq  = stats0[(srow * 4 + gg) * 2 + 1];
      float mean = sum * (1.f / H_);
      float var  = sq * (1.f / H_) - mean * mean;
      float rstd = rsqrtf(var + EPS_);
      float nv = (accb0[r] - mean) * rstd * lng0v + lnb0v;
      float a4 = __shfl_xor(nv, 4), a8 = __shfl_xor(nv, 8), a12 = __shfl_xor(nv, 12);
      float vi = (gg == 0) ? nv  : (gg == 1) ? a4  : (gg == 2) ? a8  : a12;
      float vf = (gg == 0) ? a4  : (gg == 1) ? nv  : (gg == 2) ? a12 : a8;
      float vg = (gg == 0) ? a8  : (gg == 1) ? a12 : (gg == 2) ? nv  : a4;
      float vo = (gg == 0) ? a12 : (gg == 1) ? a8  : (gg == 2) ? a4  : nv;
      float ig = sigmoidf_(vi), fg = sigmoidf_(vf), og = sigmoidf_(vo);
      float cn = c0r[r] * fg + ig * tanhf(vg);
      float xn = og * tanhf(cn) + vg;
      c0r[r] = cn;
      if (gg == 0) h0[(size_t)srow * H_ + hidx] = f2bf(xn);
    }
    __syncthreads();
    if (tid == 0) { __threadfence(); arrive_(&c2[t]); }
    {
      int tn = (t + 1 < T_) ? t + 1 : t;
      accG0[0] = 0.f; accG0[1] = 0.f; accG0[2] = 0.f; accG0[3] = 0.f;
      gemm_part<24>(accG0, ft + ((size_t)tn * N_ + rowA) * FDIM + g * 8, wb0, 128, swz, g);
    }
    if (tid == 0) spin_(&c2[t], 256);
    __syncthreads();
    __threadfence();

    // ============ phase C: G1N (exposed); stats1 publish; slack=G0H(t+1) =
    gemm_part<32>(accG1, paH0, wb1, 128, swz, g);        // G1N: h0(t)
#pragma unroll
    for (int r = 0; r < 4; ++r) accb1[r] = accG1[r] + bias1v;
#pragma unroll
    for (int r = 0; r < 4; ++r) {
      float s = accb1[r], q = s * s;
      s += __shfl_xor(s, 1); q += __shfl_xor(q, 1);
      s += __shfl_xor(s, 2); q += __shfl_xor(q, 2);
      if (hh == 0)
        *(float2*)&ptab1[(size_t)bcu * 1024 + ((rbase + r) * 4 + gg) * 2] = make_float2(s, q);
    }
    __syncthreads();
    if (tid == 0) { __threadfence(); arrive_(&c3a[t]); }
    gemm_part<32>(accG0, paH0, wb0, 0, swz, g);          // G0H(t+1): h0(t)
    if (tid == 0) spin_(&c3a[t], 256);
    __syncthreads();
    __threadfence();
    if (bcu < 128 && tid < 8) {
      int idx = (bcu * 4 + (tid >> 1)) * 2 + (tid & 1);
      float s = 0.f;
#pragma unroll 8
      for (int b = 0; b < 256; ++b) s += ptab1[(size_t)b * 1024 + idx];
      stats1[idx] = s;
    }
    __syncthreads();
    if (tid == 0) {
      __threadfence();
      if (bcu < 128) arrive_(&c3b[t]);
      spin_(&c3b[t], 128);
    }
    __syncthreads();
    __threadfence();

    // ============ phase D: cell1 -> h1(t), logits partial ================
#pragma unroll
    for (int r = 0; r < 4; ++r) {
      int srow = rbase + r;
      float sum = stats1[(srow * 4 + gg) * 2];
      float sq  = stats1[(srow * 4 + gg) * 2 + 1];
      float mean = sum * (1.f / H_);
      float var  = sq * (1.f / H_) - mean * mean;
      float rstd = rsqrtf(var + EPS_);
      float nv = (accb1[r] - mean) * rstd * lng1v + lnb1v;
      float a4 = __shfl_xor(nv, 4), a8 = __shfl_xor(nv, 8), a12 = __shfl_xor(nv, 12);
      float vi = (gg == 0) ? nv  : (gg == 1) ? a4  : (gg == 2) ? a8  : a12;
      float vf = (gg == 0) ? a4  : (gg == 1) ? nv  : (gg == 2) ? a12 : a8;
      float vg = (gg == 0) ? a8  : (gg == 1) ? a12 : (gg == 2) ? nv  : a4;
      float vo = (gg == 0) ? a12 : (gg == 1) ? a8  : (gg == 2) ? a4  : nv;
      float ig = sigmoidf_(vi), fg = sigmoidf_(vf), og = sigmoidf_(vo);
      float cn = c1r[r] * fg + ig * tanhf(vg);
      float xn = og * tanhf(cn) + vg;
      c1r[r] = cn;
      if (gg == 0) h1[(size_t)srow * H_ + hidx] = f2bf(xn);
      float cl0 = xn * fw0, cl1 = xn * fw1;
      cl0 += __shfl_xor(cl0, 1); cl1 += __shfl_xor(cl1, 1);
      cl0 += __shfl_xor(cl0, 2); cl1 += __shfl_xor(cl1, 2);
      if (vcol == 0)
        *(float2*)&ltab[(size_t)bcu * 256 + srow * 2] = make_float2(cl0, cl1);
    }
    __syncthreads();
    if (tid == 0) { __threadfence(); arrive_(&c4[t]); spin_(&c4[t], 256); }
    __syncthreads();
    __threadfence();
  }

  // epilogue: softmax for t = T-1
  if (bcu >= 128 && tid == 0) {
    int row = bcu - 128;
    float L0 = fcb[0], L1 = fcb[1];
#pragma unroll 8
    for (int b = 0; b < 256; ++b) {
      float2 v = *(const float2*)&ltab[(size_t)b * 256 + row * 2];
      L0 += v.x; L1 += v.y;
    }
    float mx = fmaxf(L0, L1);
    float e0 = expf(L0 - mx), e1 = expf(L1 - mx);
    float inv = 1.f / (e0 + e1);
    out[((size_t)row * T_ + (T_ - 1)) * 2]     = e0 * inv;
    out[((size_t)row * T_ + (T_ - 1)) * 2 + 1] = e1 * inv;
  }
}

// ---------------------------------------------------------------------------
extern "C" void kernel_launch(void* const* d_in, const int* in_sizes, int n_in,
                              void* d_out, int out_size, void* d_ws, size_t ws_size,
                              hipStream_t stream) {
  const float* x   = (const float*)d_in[0];
  const float* QnV = (const float*)d_in[1];
  const float* QlV = (const float*)d_in[2];
  const float* bng = (const float*)d_in[3];
  const float* bnb = (const float*)d_in[4];
  const float* W0  = (const float*)d_in[5];
  const float* b0  = (const float*)d_in[6];
  const float* W1  = (const float*)d_in[7];
  const float* b1  = (const float*)d_in[8];
  const float* lng = (const float*)d_in[9];
  const float* lnb = (const float*)d_in[10];
  const float* fcW = (const float*)d_in[11];
  const float* fcb = (const float*)d_in[12];
  float* out = (float*)d_out;

  float* scale  = (float*)d_ws;                  // 64
  float* shift  = scale + 64;                    // 64
  float* stats0 = shift + 64;                    // 1024
  float* stats1 = stats0 + 1024;                 // 1024
  float* ptab0  = stats1 + 1024;                 // 256*1024
  float* ptab1  = ptab0 + 256 * 1024;            // 256*1024
  float* ltab   = ptab1 + 256 * 1024;            // 256*256
  unsigned* cnts = (unsigned*)(ltab + 256 * 256); // 6*256
  u16* h0   = (u16*)(cnts + 6 * 256);
  u16* h1   = h0 + (size_t)N_ * H_;
  u16* ft   = h1 + (size_t)N_ * H_;              // 256*128*768
  u16* WtP0 = ft + (size_t)N_ * T_ * FDIM;       // 4096*1792
  u16* WtP1 = WtP0 + (size_t)G4 * K0_;           // 4096*2048

  hipMemsetAsync(h0, 0, (size_t)2 * N_ * H_ * sizeof(u16), stream);
  hipMemsetAsync(cnts, 0, 6 * 256 * sizeof(unsigned), stream);

  bn_stats_k<<<QN_, 256, 0, stream>>>(x, bng, bnb, scale, shift);
  feats_all_k<<<N_ * T_, 256, 0, stream>>>(x, scale, shift, QnV, QlV, ft);
  wconv_k<<<dim3(K0_ / 64, G4 / 64), 256, 0, stream>>>(W0, WtP0, K0_);
  wconv_k<<<dim3(K1_ / 64, G4 / 64), 256, 0, stream>>>(W1, WtP1, K1_);

  void* args[] = {
    (void*)&WtP0, (void*)&WtP1, (void*)&ft, (void*)&h0, (void*)&h1,
    (void*)&b0, (void*)&b1, (void*)&lng, (void*)&lnb,
    (void*)&fcW, (void*)&fcb, (void*)&stats0, (void*)&stats1,
    (void*)&ptab0, (void*)&ptab1, (void*)&ltab, (void*)&cnts, (void*)&out
  };
  hipLaunchCooperativeKernel((void*)persist_k, dim3(256), dim3(512), args, 0, stream);
}

// Round 5
// 15195.427 us; speedup vs baseline: 5.1135x; 5.1135x over previous
//
#include <hip/hip_runtime.h>
#include <math.h>

// ---------------------------------------------------------------------------
// LSTMModel round 5: persistent cooperative kernel, FENCE-FREE sync protocol.
// All cross-block data via relaxed agent-scope (sc1) atomic ld/st; barriers
// via 8 split epoch counters; only 2 invalidate-only acquire fences per step
// (before bulk cached reads of freshly-written h). No __threadfence, no
// grid.sync, no buffer_wbl2 anywhere in the loop.
// ---------------------------------------------------------------------------

#define N_   128
#define T_   256
#define QN_  16
#define INX  24
#define H_   1024
#define G4   4096
#define FDIM 768
#define EPS_ 1e-5f
#define K0_  1792
#define K1_  2048
#define W1OFF (16 * K0_)

typedef unsigned short u16;
typedef unsigned int u32;
typedef unsigned long long u64;
typedef __attribute__((ext_vector_type(8))) short bf16x8;
typedef __attribute__((ext_vector_type(4))) float f32x4;

__device__ __forceinline__ float sigmoidf_(float v) { return 1.0f / (1.0f + expf(-v)); }

__device__ __forceinline__ u16 f2bf(float f) {
  unsigned u = __float_as_uint(f);
  u += 0x7fffu + ((u >> 16) & 1u);
  return (u16)(u >> 16);
}

// agent-scope (cross-XCD coherent, sc1) point accesses — no fences needed
__device__ __forceinline__ void st_u64g(void* p, u64 v) {
  __hip_atomic_store((u64*)p, v, __ATOMIC_RELAXED, __HIP_MEMORY_SCOPE_AGENT);
}
__device__ __forceinline__ u64 ld_u64g(const void* p) {
  return __hip_atomic_load((const u64*)p, __ATOMIC_RELAXED, __HIP_MEMORY_SCOPE_AGENT);
}
__device__ __forceinline__ u64 packf2(float a, float b) {
  return ((u64)__float_as_uint(b) << 32) | __float_as_uint(a);
}

// ---- BatchNorm stats over the (N*T, 16) numeric block --------------------
__global__ __launch_bounds__(256) void bn_stats_k(const float* __restrict__ x,
    const float* __restrict__ gamma, const float* __restrict__ beta,
    float* __restrict__ scale, float* __restrict__ shift) {
  int q = blockIdx.x;
  int tid = threadIdx.x;
  float s = 0.f, s2 = 0.f;
  for (int r = tid; r < N_ * T_; r += 256) {
    float v = x[(size_t)r * INX + q];
    s += v; s2 += v * v;
  }
  for (int off = 32; off; off >>= 1) { s += __shfl_down(s, off); s2 += __shfl_down(s2, off); }
  __shared__ float red[2][4];
  int w = tid >> 6;
  if ((tid & 63) == 0) { red[0][w] = s; red[1][w] = s2; }
  __syncthreads();
  if (tid == 0) {
    float S = 0.f, S2 = 0.f;
    for (int i = 0; i < 4; ++i) { S += red[0][i]; S2 += red[1][i]; }
    float m   = S  / (float)(N_ * T_);
    float var = S2 / (float)(N_ * T_) - m * m;
    float rs  = rsqrtf(var + EPS_);
    scale[q] = rs * gamma[q];
    shift[q] = beta[q] - m * rs * gamma[q];
  }
}

// ---- Feature build for ALL steps: ft[t][n][768] bf16 ---------------------
__global__ __launch_bounds__(256) void feats_all_k(const float* __restrict__ x,
    const float* __restrict__ scale, const float* __restrict__ shift,
    const float* __restrict__ QnV, const float* __restrict__ QlV,
    u16* __restrict__ ft) {
  int rid = blockIdx.x;              // t*128 + n
  int t = rid >> 7, n = rid & 127;
  const float* xr = x + ((size_t)n * T_ + t) * INX;
  u16* frow = ft + (size_t)rid * FDIM;
  for (int f = threadIdx.x; f < FDIM; f += 256) {
    int d = f & 31;
    float v;
    if (f < 512) {
      int q = f >> 5;
      v = (xr[q] * scale[q] + shift[q]) * QnV[q * 32 + d];
    } else {
      int cg_ = (f - 512) >> 5;
      int idx = (int)xr[QN_ + cg_] + cg_ * 100;
      v = QlV[idx * 32 + d];
    }
    frow[f] = f2bf(v);
  }
}

// ---- Weight convert: W[k][col] fp32 -> WtP[(bcu*16+v)][k] bf16 -----------
__global__ __launch_bounds__(256) void wconv_k(const float* __restrict__ W,
                                               u16* __restrict__ WtP, int K) {
  __shared__ u16 L[64][72];
  int tid = threadIdx.x;
  int k0 = blockIdx.x * 64, n0 = blockIdx.y * 64;
#pragma unroll
  for (int it = 0; it < 16; ++it) {
    int e = it * 256 + tid;
    int r = e >> 6, c = e & 63;
    L[r][c] = f2bf(W[(size_t)(k0 + r) * G4 + n0 + c]);
  }
  __syncthreads();
  int n = tid >> 2, ks = (tid & 3) << 4;
  int col = n0 + n;
  int bcu = (col & 1023) >> 2;
  int v   = (col >> 10) * 4 + (col & 3);
  u16* dst = WtP + ((size_t)(bcu * 16 + v)) * K + k0 + ks;
#pragma unroll
  for (int j = 0; j < 16; ++j) dst[j] = L[ks + j][n];
}

// ---- barrier primitives: 8 split monotonic counters, 64B apart -----------
#define CNT(bar, sub) cnts[((bar) * 8 + (sub)) * 16]
__device__ __forceinline__ void rel_waitcnt() {
  asm volatile("s_waitcnt vmcnt(0)" ::: "memory");
}
__device__ __forceinline__ void arrive_(u32* cnts, int bar, int sub) {
  __hip_atomic_fetch_add(&CNT(bar, sub), 1u, __ATOMIC_RELAXED, __HIP_MEMORY_SCOPE_AGENT);
}
__device__ __forceinline__ void spinwait_(u32* cnts, int bar, int nsub, u32 tgt, int tid) {
  if (tid < nsub) {
    while (__hip_atomic_load(&CNT(bar, tid), __ATOMIC_RELAXED, __HIP_MEMORY_SCOPE_AGENT) < tgt)
      __builtin_amdgcn_s_sleep(1);
  }
  __syncthreads();
}
__device__ __forceinline__ void acq_fence_(int tid) {
  if (tid < 64) __builtin_amdgcn_fence(__ATOMIC_ACQUIRE, "agent");  // buffer_inv, no wb
  __syncthreads();
}

// ---- K-partial MFMA: acc += A[rowA, ...] @ Wlds ---------------------------
template<int NK>
__device__ __forceinline__ void gemm_part(f32x4& acc, const u16* __restrict__ aBase,
                                          const u16* wRow, int cb, int swz, int g) {
#pragma unroll 8
  for (int kc = 0; kc < NK; ++kc) {
    bf16x8 a = *(const bf16x8*)(aBase + kc * 32);
    bf16x8 b = *(const bf16x8*)(wRow + (((cb + kc * 4 + g) ^ swz) << 3));
    acc = __builtin_amdgcn_mfma_f32_16x16x32_bf16(a, b, acc, 0, 0, 0);
  }
}

// ---- The persistent recurrence kernel ------------------------------------
__global__ __launch_bounds__(512, 2) void persist_k(
    const u16* __restrict__ WtP0, const u16* __restrict__ WtP1,
    const u16* __restrict__ ft,
    u16* __restrict__ h0, u16* __restrict__ h1,
    const float* __restrict__ b0, const float* __restrict__ b1,
    const float* __restrict__ lng, const float* __restrict__ lnb,
    const float* __restrict__ fcW, const float* __restrict__ fcb,
    float* __restrict__ stats0, float* __restrict__ stats1,
    float* __restrict__ ptab0, float* __restrict__ ptab1,
    float* __restrict__ ltab, u32* __restrict__ cnts,
    float* __restrict__ out) {
  __shared__ u16 wlds[16 * K0_ + 16 * K1_];   // 120 KiB
  const int bcu = blockIdx.x, tid = threadIdx.x;
  const int wave = tid >> 6, lane = tid & 63;
  const int vcol = lane & 15, g = lane >> 4;
  const int gg = vcol >> 2, hh = vcol & 3;
  const int swz = vcol & 7;
  const int rowA  = wave * 16 + vcol;
  const int rbase = wave * 16 + g * 4;
  const int hidx  = bcu * 4 + hh;
  const int col0  = gg * 1024 + hidx;
  const int sub   = bcu >> 5;

  // ---- one-time: weight slices global -> LDS (XOR chunk swizzle) ----
  for (int i = 0; i < 15; ++i) {
    int cid = tid + i * 512;
    if (cid < 3584) {
      int v = cid / 224, ck = cid - v * 224;
      *(bf16x8*)&wlds[v * K0_ + ((ck ^ (v & 7)) << 3)] =
          *(const bf16x8*)&WtP0[((size_t)(bcu * 16 + v)) * K0_ + (ck << 3)];
    } else {
      int c2i = cid - 3584;
      int v = c2i >> 8, ck = c2i & 255;
      *(bf16x8*)&wlds[W1OFF + v * K1_ + ((ck ^ (v & 7)) << 3)] =
          *(const bf16x8*)&WtP1[((size_t)(bcu * 16 + v)) * K1_ + (ck << 3)];
    }
  }
  __syncthreads();

  const float bias0v = b0[col0], bias1v = b1[col0];
  const float lng0v = lng[col0],      lnb0v = lnb[col0];
  const float lng1v = lng[G4 + col0], lnb1v = lnb[G4 + col0];
  const float fw0 = fcW[hidx * 2], fw1 = fcW[hidx * 2 + 1];

  float c0r[4] = {0.f, 0.f, 0.f, 0.f};
  float c1r[4] = {0.f, 0.f, 0.f, 0.f};

  const u16* paH0 = h0 + (size_t)rowA * H_ + g * 8;
  const u16* paH1 = h1 + (size_t)rowA * H_ + g * 8;
  const u16* wb0 = &wlds[vcol * K0_];
  const u16* wb1 = &wlds[W1OFF + vcol * K1_];

  // prologue: accG0 = G0F(0)  (h0 == 0 so G0H(0) contributes nothing)
  f32x4 accG0 = {0.f, 0.f, 0.f, 0.f};
  gemm_part<24>(accG0, ft + (size_t)rowA * FDIM + g * 8, wb0, 128, swz, g);

  f32x4 accb0, accb1;

  for (int t = 0; t < T_; ++t) {
    const u32 tgt = (u32)(t + 1) * 32u;

    // ============ phase A: publish ptab0; slack = G1H(h1(t-1)) ===========
#pragma unroll
    for (int r = 0; r < 4; ++r) accb0[r] = accG0[r] + bias0v;
#pragma unroll
    for (int r = 0; r < 4; ++r) {
      float s = accb0[r], q = s * s;
      s += __shfl_xor(s, 1); q += __shfl_xor(q, 1);
      s += __shfl_xor(s, 2); q += __shfl_xor(q, 2);
      if (hh == 0)
        st_u64g(&ptab0[(size_t)bcu * 1024 + ((rbase + r) * 4 + gg) * 2], packf2(s, q));
    }
    rel_waitcnt();
    __syncthreads();
    if (tid == 0) arrive_(cnts, 0, sub);
    f32x4 accG1 = {0.f, 0.f, 0.f, 0.f};
    gemm_part<32>(accG1, paH1, wb1, 0, swz, g);          // normal cached loads
    spinwait_(cnts, 0, 8, tgt, tid);

    // reduce window: blocks 0..127 reduce stats0; 128..255 softmax(t-1)
    if (bcu < 128) {
      if (wave < 4) {
        int e = bcu * 4 + wave;                          // f2 entry 0..511
        float s = 0.f, q = 0.f;
#pragma unroll
        for (int j = 0; j < 4; ++j) {
          u64 v = ld_u64g(&ptab0[(size_t)(lane * 4 + j) * 1024 + e * 2]);
          s += __uint_as_float((u32)v);
          q += __uint_as_float((u32)(v >> 32));
        }
        for (int off = 32; off; off >>= 1) { s += __shfl_xor(s, off); q += __shfl_xor(q, off); }
        if (lane == 0) st_u64g(&stats0[e * 2], packf2(s, q));
      }
    } else if (t > 0 && wave == 0) {
      int row = bcu - 128;
      float L0 = 0.f, L1 = 0.f;
#pragma unroll
      for (int j = 0; j < 4; ++j) {
        u64 v = ld_u64g(&ltab[(size_t)(lane * 4 + j) * 256 + row * 2]);
        L0 += __uint_as_float((u32)v);
        L1 += __uint_as_float((u32)(v >> 32));
      }
      for (int off = 32; off; off >>= 1) { L0 += __shfl_xor(L0, off); L1 += __shfl_xor(L1, off); }
      if (lane == 0) {
        L0 += fcb[0]; L1 += fcb[1];
        float mx = fmaxf(L0, L1);
        float e0 = expf(L0 - mx), e1 = expf(L1 - mx);
        float inv = 1.f / (e0 + e1);
        st_u64g(&out[((size_t)row * T_ + (t - 1)) * 2], packf2(e0 * inv, e1 * inv));
      }
    }
    rel_waitcnt();
    __syncthreads();
    if (tid == 0 && bcu < 128) arrive_(cnts, 1, sub);
    spinwait_(cnts, 1, 4, tgt, tid);

    // ============ phase B: cell0 -> h0(t); slack = G0F(t+1) ==============
    {
      u64 sv[4];
#pragma unroll
      for (int r = 0; r < 4; ++r) sv[r] = ld_u64g(&stats0[((rbase + r) * 4 + gg) * 2]);
#pragma unroll
      for (int r = 0; r < 4; ++r) {
        int srow = rbase + r;
        float sum = __uint_as_float((u32)sv[r]);
        float sq  = __uint_as_float((u32)(sv[r] >> 32));
        float mean = sum * (1.f / H_);
        float var  = sq * (1.f / H_) - mean * mean;
        float rstd = rsqrtf(var + EPS_);
        float nv = (accb0[r] - mean) * rstd * lng0v + lnb0v;
        float a4 = __shfl_xor(nv, 4), a8 = __shfl_xor(nv, 8), a12 = __shfl_xor(nv, 12);
        float vi = (gg == 0) ? nv  : (gg == 1) ? a4  : (gg == 2) ? a8  : a12;
        float vf = (gg == 0) ? a4  : (gg == 1) ? nv  : (gg == 2) ? a12 : a8;
        float vg = (gg == 0) ? a8  : (gg == 1) ? a12 : (gg == 2) ? nv  : a4;
        float vo = (gg == 0) ? a12 : (gg == 1) ? a8  : (gg == 2) ? a4  : nv;
        float ig = sigmoidf_(vi), fg = sigmoidf_(vf), og = sigmoidf_(vo);
        float cn = c0r[r] * fg + ig * tanhf(vg);
        float xn = og * tanhf(cn) + vg;
        c0r[r] = cn;
        u32 xv = f2bf(xn);
        u32 other = __shfl_xor((int)xv, 1);
        u32 pairv = (vcol & 1) ? (other | (xv << 16)) : (xv | (other << 16));
        u32 p2 = __shfl_xor((int)pairv, 2);
        if (vcol == 0)
          st_u64g(&h0[(size_t)srow * H_ + bcu * 4], ((u64)p2 << 32) | pairv);
      }
    }
    rel_waitcnt();
    __syncthreads();
    if (tid == 0) arrive_(cnts, 2, sub);
    {
      int tn = (t + 1 < T_) ? t + 1 : t;
      accG0[0] = 0.f; accG0[1] = 0.f; accG0[2] = 0.f; accG0[3] = 0.f;
      gemm_part<24>(accG0, ft + ((size_t)tn * N_ + rowA) * FDIM + g * 8, wb0, 128, swz, g);
    }
    spinwait_(cnts, 2, 8, tgt, tid);
    acq_fence_(tid);                                     // h0(t) now readable cached

    // ============ phase C: G1N exposed; publish ptab1; slack = G0H(t+1) ==
    gemm_part<32>(accG1, paH0, wb1, 128, swz, g);        // h0(t)
#pragma unroll
    for (int r = 0; r < 4; ++r) accb1[r] = accG1[r] + bias1v;
#pragma unroll
    for (int r = 0; r < 4; ++r) {
      float s = accb1[r], q = s * s;
      s += __shfl_xor(s, 1); q += __shfl_xor(q, 1);
      s += __shfl_xor(s, 2); q += __shfl_xor(q, 2);
      if (hh == 0)
        st_u64g(&ptab1[(size_t)bcu * 1024 + ((rbase + r) * 4 + gg) * 2], packf2(s, q));
    }
    rel_waitcnt();
    __syncthreads();
    if (tid == 0) arrive_(cnts, 3, sub);
    gemm_part<32>(accG0, paH0, wb0, 0, swz, g);          // G0H(t+1): h0(t)
    spinwait_(cnts, 3, 8, tgt, tid);

    if (bcu < 128 && wave < 4) {
      int e = bcu * 4 + wave;
      float s = 0.f, q = 0.f;
#pragma unroll
      for (int j = 0; j < 4; ++j) {
        u64 v = ld_u64g(&ptab1[(size_t)(lane * 4 + j) * 1024 + e * 2]);
        s += __uint_as_float((u32)v);
        q += __uint_as_float((u32)(v >> 32));
      }
      for (int off = 32; off; off >>= 1) { s += __shfl_xor(s, off); q += __shfl_xor(q, off); }
      if (lane == 0) st_u64g(&stats1[e * 2], packf2(s, q));
    }
    rel_waitcnt();
    __syncthreads();
    if (tid == 0 && bcu < 128) arrive_(cnts, 4, sub);
    spinwait_(cnts, 4, 4, tgt, tid);

    // ============ phase D: cell1 -> h1(t), logits partial ================
    {
      u64 sv[4];
#pragma unroll
      for (int r = 0; r < 4; ++r) sv[r] = ld_u64g(&stats1[((rbase + r) * 4 + gg) * 2]);
#pragma unroll
      for (int r = 0; r < 4; ++r) {
        int srow = rbase + r;
        float sum = __uint_as_float((u32)sv[r]);
        float sq  = __uint_as_float((u32)(sv[r] >> 32));
        float mean = sum * (1.f / H_);
        float var  = sq * (1.f / H_) - mean * mean;
        float rstd = rsqrtf(var + EPS_);
        float nv = (accb1[r] - mean) * rstd * lng1v + lnb1v;
        float a4 = __shfl_xor(nv, 4), a8 = __shfl_xor(nv, 8), a12 = __shfl_xor(nv, 12);
        float vi = (gg == 0) ? nv  : (gg == 1) ? a4  : (gg == 2) ? a8  : a12;
        float vf = (gg == 0) ? a4  : (gg == 1) ? nv  : (gg == 2) ? a12 : a8;
        float vg = (gg == 0) ? a8  : (gg == 1) ? a12 : (gg == 2) ? nv  : a4;
        float vo = (gg == 0) ? a12 : (gg == 1) ? a8  : (gg == 2) ? a4  : nv;
        float ig = sigmoidf_(vi), fg = sigmoidf_(vf), og = sigmoidf_(vo);
        float cn = c1r[r] * fg + ig * tanhf(vg);
        float xn = og * tanhf(cn) + vg;
        c1r[r] = cn;
        u32 xv = f2bf(xn);
        u32 other = __shfl_xor((int)xv, 1);
        u32 pairv = (vcol & 1) ? (other | (xv << 16)) : (xv | (other << 16));
        u32 p2 = __shfl_xor((int)pairv, 2);
        if (vcol == 0)
          st_u64g(&h1[(size_t)srow * H_ + bcu * 4], ((u64)p2 << 32) | pairv);
        float cl0 = xn * fw0, cl1 = xn * fw1;
        cl0 += __shfl_xor(cl0, 1); cl1 += __shfl_xor(cl1, 1);
        cl0 += __shfl_xor(cl0, 2); cl1 += __shfl_xor(cl1, 2);
        if (vcol == 0)
          st_u64g(&ltab[(size_t)bcu * 256 + srow * 2], packf2(cl0, cl1));
      }
    }
    rel_waitcnt();
    __syncthreads();
    if (tid == 0) arrive_(cnts, 5, sub);
    spinwait_(cnts, 5, 8, tgt, tid);
    acq_fence_(tid);                                     // h1(t) readable next step
  }

  // epilogue: softmax for t = T-1
  if (bcu >= 128 && wave == 0) {
    int row = bcu - 128;
    float L0 = 0.f, L1 = 0.f;
#pragma unroll
    for (int j = 0; j < 4; ++j) {
      u64 v = ld_u64g(&ltab[(size_t)(lane * 4 + j) * 256 + row * 2]);
      L0 += __uint_as_float((u32)v);
      L1 += __uint_as_float((u32)(v >> 32));
    }
    for (int off = 32; off; off >>= 1) { L0 += __shfl_xor(L0, off); L1 += __shfl_xor(L1, off); }
    if (lane == 0) {
      L0 += fcb[0]; L1 += fcb[1];
      float mx = fmaxf(L0, L1);
      float e0 = expf(L0 - mx), e1 = expf(L1 - mx);
      float inv = 1.f / (e0 + e1);
      st_u64g(&out[((size_t)row * T_ + (T_ - 1)) * 2], packf2(e0 * inv, e1 * inv));
    }
  }
}

// ---------------------------------------------------------------------------
extern "C" void kernel_launch(void* const* d_in, const int* in_sizes, int n_in,
                              void* d_out, int out_size, void* d_ws, size_t ws_size,
                              hipStream_t stream) {
  const float* x   = (const float*)d_in[0];
  const float* QnV = (const float*)d_in[1];
  const float* QlV = (const float*)d_in[2];
  const float* bng = (const float*)d_in[3];
  const float* bnb = (const float*)d_in[4];
  const float* W0  = (const float*)d_in[5];
  const float* b0  = (const float*)d_in[6];
  const float* W1  = (const float*)d_in[7];
  const float* b1  = (const float*)d_in[8];
  const float* lng = (const float*)d_in[9];
  const float* lnb = (const float*)d_in[10];
  const float* fcW = (const float*)d_in[11];
  const float* fcb = (const float*)d_in[12];
  float* out = (float*)d_out;

  float* scale  = (float*)d_ws;                   // 64
  float* shift  = scale + 64;                     // 64
  float* stats0 = shift + 64;                     // 1024
  float* stats1 = stats0 + 1024;                  // 1024
  float* ptab0  = stats1 + 1024;                  // 256*1024
  float* ptab1  = ptab0 + 256 * 1024;             // 256*1024
  float* ltab   = ptab1 + 256 * 1024;             // 256*256
  u32* cnts = (u32*)(ltab + 256 * 256);           // 6*8*16 = 768 u32 (pad 1024)
  u16* h0   = (u16*)(cnts + 1024);
  u16* h1   = h0 + (size_t)N_ * H_;
  u16* ft   = h1 + (size_t)N_ * H_;               // 256*128*768
  u16* WtP0 = ft + (size_t)N_ * T_ * FDIM;        // 4096*1792
  u16* WtP1 = WtP0 + (size_t)G4 * K0_;            // 4096*2048

  hipMemsetAsync(h0, 0, (size_t)2 * N_ * H_ * sizeof(u16), stream);
  hipMemsetAsync(cnts, 0, 1024 * sizeof(u32), stream);

  bn_stats_k<<<QN_, 256, 0, stream>>>(x, bng, bnb, scale, shift);
  feats_all_k<<<N_ * T_, 256, 0, stream>>>(x, scale, shift, QnV, QlV, ft);
  wconv_k<<<dim3(K0_ / 64, G4 / 64), 256, 0, stream>>>(W0, WtP0, K0_);
  wconv_k<<<dim3(K1_ / 64, G4 / 64), 256, 0, stream>>>(W1, WtP1, K1_);

  void* args[] = {
    (void*)&WtP0, (void*)&WtP1, (void*)&ft, (void*)&h0, (void*)&h1,
    (void*)&b0, (void*)&b1, (void*)&lng, (void*)&lnb,
    (void*)&fcW, (void*)&fcb, (void*)&stats0, (void*)&stats1,
    (void*)&ptab0, (void*)&ptab1, (void*)&ltab, (void*)&cnts, (void*)&out
  };
  hipLaunchCooperativeKernel((void*)persist_k, dim3(256), dim3(512), args, 0, stream);
}